// Round 8
// baseline (330.820 us; speedup 1.0000x reference)
//
#include <hip/hip_runtime.h>
#include <hip/hip_bf16.h>

// B=128, S=256, E=768, C=4; M = B*S = 32768.
// 4 launches:
//  prep:  qW1 partials (K-split x4) | W1t/W2t transposes | segB=bf16(segments)
//  K2:    H1b[32768,768]bf16 = gelu(segB @ W1t^T + b1 + sum qW1p[bag])  (MFMA, 128x256 blocks)
//  K3:    H2b[32768,384]bf16 = gelu(H1b @ W2t^T + b2)                   (MFMA, 128x128 blocks)
//  head:  out[128,4] = aggregate(softmax(H2b @ W3 + b3))

typedef __attribute__((ext_vector_type(8))) short short8;
typedef __attribute__((ext_vector_type(8))) unsigned short ushort8;
typedef __attribute__((ext_vector_type(4))) float f32x4;
typedef __attribute__((ext_vector_type(16))) float f32x16;

__device__ __forceinline__ unsigned short f2bf(float f) {
    union { float f; unsigned int u; } c; c.f = f;
    unsigned int u = c.u;
    unsigned int r = (u + 0x7FFFu + ((u >> 16) & 1u)) >> 16;  // RNE
    return (unsigned short)r;
}
__device__ __forceinline__ float bf2f(unsigned short u) {
    union { unsigned int u; float f; } c; c.u = ((unsigned int)u) << 16;
    return c.f;
}
__device__ __forceinline__ float gelu_fast(float x) {
    float x2 = x * x;
    float y2 = 1.5957691216057308f * (x + 0.044715f * x2 * x);
    float e = __expf(y2);
    float t = 1.0f - 2.0f * __builtin_amdgcn_rcpf(e + 1.0f);
    return 0.5f * x * (1.0f + t);
}

typedef const __attribute__((address_space(1))) void* gas_t;
typedef __attribute__((address_space(3))) void* las_t;
__device__ __forceinline__ void g2l16(const void* g, void* l) {
    __builtin_amdgcn_global_load_lds((gas_t)g, (las_t)l, 16, 0, 0);
}

// ---------------- fused prep kernel ----------------
// blocks [0,96):        qW1 partials: 4 K-slices x (12 n x 2 m)
// blocks [96,240):      transpose W1[768:] -> W1t
// blocks [240,312):     transpose W2 -> W2t
// blocks [312,12600):   conv segments -> segB bf16
#define PREP_Q    96
#define PREP_TR1E 240
#define PREP_TR2E 312
#define PREP_END  12600

__global__ __launch_bounds__(256) void prep_kernel(
    const float* __restrict__ segments, unsigned short* __restrict__ segB,
    const float* __restrict__ W1, unsigned short* __restrict__ W1t,
    const float* __restrict__ W2, unsigned short* __restrict__ W2t,
    const float* __restrict__ questions, float* __restrict__ qW1p)
{
    __shared__ __align__(16) char sh[16640];
    const int bid = blockIdx.x, tid = threadIdx.x;

    if (bid < PREP_Q) {
        const int s = bid / 24, rem = bid % 24;
        const int n0 = (rem % 12) * 64, m0 = (rem / 12) * 64;
        float (*As)[64] = (float(*)[64])sh;
        float (*Bs)[64] = (float(*)[64])(sh + 4096);
        const int tn = tid & 15, tm = tid >> 4;
        float acc[4][4] = {};
        const int la_m = tid >> 2;
        const int la_k = (tid & 3) << 2;
        const int lb_k = tid >> 4;
        const int lb_n = (tid & 15) << 2;
        const float* Aptr = questions + (size_t)(m0 + la_m) * 768 + la_k;
        const float* Bptr = W1 + (size_t)lb_k * 768 + n0 + lb_n;
        const int kbeg = s * 192, kend = kbeg + 192;
        for (int k0 = kbeg; k0 < kend; k0 += 16) {
            float4 av = *(const float4*)(Aptr + k0);
            float4 bv = *(const float4*)(Bptr + (size_t)k0 * 768);
            As[la_k + 0][la_m] = av.x;
            As[la_k + 1][la_m] = av.y;
            As[la_k + 2][la_m] = av.z;
            As[la_k + 3][la_m] = av.w;
            *(float4*)&Bs[lb_k][lb_n] = bv;
            __syncthreads();
            #pragma unroll
            for (int k = 0; k < 16; k++) {
                float4 a = *(const float4*)&As[k][tm << 2];
                float4 b = *(const float4*)&Bs[k][tn << 2];
                float ar[4] = {a.x, a.y, a.z, a.w};
                float br[4] = {b.x, b.y, b.z, b.w};
                #pragma unroll
                for (int i = 0; i < 4; i++)
                    #pragma unroll
                    for (int j = 0; j < 4; j++)
                        acc[i][j] += ar[i] * br[j];
            }
            __syncthreads();
        }
        float* outp = qW1p + (size_t)s * 128 * 768;
        #pragma unroll
        for (int i = 0; i < 4; i++) {
            int row = m0 + (tm << 2) + i;
            int colBase = n0 + (tn << 2);
            *(float4*)&outp[(size_t)row * 768 + colBase] =
                make_float4(acc[i][0], acc[i][1], acc[i][2], acc[i][3]);
        }
        return;
    }

    if (bid < PREP_TR2E) {
        const float* in; unsigned short* outp; int R, C, bx, by;
        if (bid < PREP_TR1E) {
            int idx = bid - PREP_Q; bx = idx % 12; by = idx / 12;
            in = W1 + 768 * 768; outp = W1t; R = 768; C = 768;
        } else {
            int idx = bid - PREP_TR1E; bx = idx % 6; by = idx / 6;
            in = W2; outp = W2t; R = 768; C = 384;
        }
        float (*t)[65] = (float(*)[65])sh;
        int r0 = by * 64, c0 = bx * 64;
        int tx = tid & 63, ty = tid >> 6;
        #pragma unroll
        for (int p = 0; p < 16; p++) {
            int row = ty * 16 + p;
            t[row][tx] = in[(size_t)(r0 + row) * C + c0 + tx];
        }
        __syncthreads();
        #pragma unroll
        for (int p = 0; p < 16; p++) {
            int orow = ty * 16 + p;
            outp[(size_t)(c0 + orow) * R + r0 + tx] = f2bf(t[tx][orow]);
        }
        return;
    }

    {
        long i = (long)(bid - PREP_TR2E) * 256 + tid;
        const float4* in = (const float4*)segments;
        float4 a = in[2 * i], b = in[2 * i + 1];
        ushort8 o;
        o[0] = f2bf(a.x); o[1] = f2bf(a.y); o[2] = f2bf(a.z); o[3] = f2bf(a.w);
        o[4] = f2bf(b.x); o[5] = f2bf(b.y); o[6] = f2bf(b.z); o[7] = f2bf(b.w);
        *(ushort8*)(segB + i * 8) = o;
    }
}

// ---------------- bf16 MFMA GEMM, B^T input, 32x32x16, BK=64, XOR-swizzled LDS ----
// Templated on TJ (wave-tile cols / 32). Block = 128 rows x (TJ*64) cols, 4 waves,
// wave-tile 64 x (TJ*32). Epilogue runs TJ/2 passes of 128 cols; a wave writes in
// pass h iff its columns fall in [h*128, h*128+128)  — i.e. (wcol>>7)==h.
// (r7 bug: gating with (wave>>1)==h dropped waves 2,3 for TJ=2.)
template<int TJ>
__global__ __launch_bounds__(256) void mfma_gemm_bt(
    const unsigned short* __restrict__ A,    // [M,K] bf16
    const unsigned short* __restrict__ Bt,   // [N,K] bf16
    const float* __restrict__ bias,          // [N] or null
    const float* __restrict__ rowAdd,        // [4][M/256, N] partials or null
    unsigned short* __restrict__ Cout,       // [M,N] bf16
    int M, int N, int K, int applyGelu)
{
    constexpr int BN = TJ * 64;
    __shared__ __align__(16) unsigned short smem[8192 + BN * 64];
    unsigned short* As = smem;             // [128][64] swizzled
    unsigned short* Bs = smem + 8192;      // [BN][64] swizzled
    const int tid = threadIdx.x;
    const int wave = tid >> 6, lane = tid & 63;
    const int m0 = blockIdx.y * 128, n0 = blockIdx.x * BN;
    const int wm = (wave & 1) * 64;
    const int wcol = (wave >> 1) * (TJ * 32);

    f32x16 acc[2][TJ] = {};

    const int srow = tid >> 3;
    const int schunk = (tid & 7) ^ (srow & 7);
    const unsigned short* Ag = A + (size_t)(m0 + srow) * K + schunk * 8;
    const unsigned short* Bg = Bt + (size_t)(n0 + srow) * K + schunk * 8;
    unsigned short* Al = As + tid * 8;
    unsigned short* Bl = Bs + tid * 8;

    const int fm = lane & 31, fq = lane >> 5;
    const int fs = fm & 7;

    for (int k0 = 0; k0 < K; k0 += 64) {
        #pragma unroll
        for (int r = 0; r < 4; r++)
            g2l16(Ag + k0 + (size_t)(32 * r) * K, Al + r * 2048);
        #pragma unroll
        for (int r = 0; r < 2 * TJ; r++)
            g2l16(Bg + k0 + (size_t)(32 * r) * K, Bl + r * 2048);
        __syncthreads();

        #pragma unroll
        for (int kh = 0; kh < 4; kh++) {
            const int kc = (((kh << 1) | fq) ^ fs) * 8;
            short8 af[2], bfr[TJ];
            #pragma unroll
            for (int i = 0; i < 2; i++)
                af[i] = *(const short8*)&As[(wm + i * 32 + fm) * 64 + kc];
            #pragma unroll
            for (int j = 0; j < TJ; j++)
                bfr[j] = *(const short8*)&Bs[(wcol + j * 32 + fm) * 64 + kc];
            #pragma unroll
            for (int i = 0; i < 2; i++)
                #pragma unroll
                for (int j = 0; j < TJ; j++)
                    acc[i][j] = __builtin_amdgcn_mfma_f32_32x32x16_bf16(
                        af[i], bfr[j], acc[i][j], 0, 0, 0);
        }
        __syncthreads();
    }

    // Epilogue in TJ/2 passes of 128x128 through LDS.
    // C/D layout: col=lane&31, row=(reg&3)+8*(reg>>2)+4*(lane>>5)
    const float* radd = rowAdd ? (rowAdd + (size_t)(m0 >> 8) * N) : nullptr;
    #pragma unroll
    for (int h = 0; h < TJ / 2; h++) {
        if ((wcol >> 7) == h) {
            #pragma unroll
            for (int j = 0; j < TJ; j++) {
                int coll = (wcol & 127) + j * 32 + fm;   // col within this 128-wide pass
                int col = n0 + h * 128 + coll;
                float add = bias ? bias[col] : 0.0f;
                if (radd)
                    add += radd[col] + radd[col + 98304] +
                           radd[col + 2 * 98304] + radd[col + 3 * 98304];
                #pragma unroll
                for (int i = 0; i < 2; i++) {
                    int rbase = wm + i * 32 + 4 * fq;
                    #pragma unroll
                    for (int reg = 0; reg < 16; reg++) {
                        int rowl = rbase + (reg & 3) + 8 * (reg >> 2);
                        float v = acc[i][j][reg] + add;
                        if (applyGelu) v = gelu_fast(v);
                        smem[rowl * 128 + coll] = f2bf(v);
                    }
                }
            }
        }
        __syncthreads();
        #pragma unroll
        for (int it = 0; it < 8; it++) {
            int idx = it * 256 + tid;
            int r = idx >> 4, cc = (idx & 15) * 8;
            *(ushort8*)&Cout[(size_t)(m0 + r) * N + n0 + h * 128 + cc] =
                *(const ushort8*)&smem[r * 128 + cc];
        }
        __syncthreads();
    }
}

// ---------------- fused head: layer3 + softmax + aggregation ----------------
__device__ __forceinline__ float4 f4mul(float4 a, float4 b) {
    return make_float4(a.x * b.x, a.y * b.y, a.z * b.z, a.w * b.w);
}
__device__ float4 scan_prod(float4 v, float4* buf, int tid) {
    __syncthreads();
    buf[tid] = v;
    __syncthreads();
    #pragma unroll
    for (int off = 1; off < 256; off <<= 1) {
        float4 o = (tid >= off) ? buf[tid - off] : make_float4(1.f, 1.f, 1.f, 1.f);
        __syncthreads();
        v = f4mul(v, o);
        buf[tid] = v;
        __syncthreads();
    }
    return v;
}

__global__ __launch_bounds__(256) void head_kernel(
    const unsigned short* __restrict__ H2, const float* __restrict__ W3,
    const float* __restrict__ b3, const int* __restrict__ nseg,
    float* __restrict__ out)
{
    __shared__ float4 buf[256];
    __shared__ float4 w3s[384];
    const int b = blockIdx.x, tid = threadIdx.x;
    for (int i = tid; i < 384; i += 256) w3s[i] = ((const float4*)W3)[i];
    __syncthreads();

    const unsigned short* hrow = H2 + (size_t)(b * 256 + tid) * 384;
    float4 acc = make_float4(b3[0], b3[1], b3[2], b3[3]);
    #pragma unroll
    for (int kk = 0; kk < 48; kk++) {
        ushort8 u = *(const ushort8*)(hrow + kk * 8);
        #pragma unroll
        for (int j = 0; j < 8; j++) {
            float h = bf2f(u[j]);
            float4 w = w3s[kk * 8 + j];
            acc.x += h * w.x; acc.y += h * w.y; acc.z += h * w.z; acc.w += h * w.w;
        }
    }
    float m = fmaxf(fmaxf(acc.x, acc.y), fmaxf(acc.z, acc.w));
    float e0 = __expf(acc.x - m), e1 = __expf(acc.y - m),
          e2 = __expf(acc.z - m), e3 = __expf(acc.w - m);
    float inv = 1.0f / (e0 + e1 + e2 + e3);
    float4 p = make_float4(e0 * inv, e1 * inv, e2 * inv, e3 * inv);

    const int n = nseg[b];
    const float4 ones = make_float4(1.f, 1.f, 1.f, 1.f);
    bool msk = tid < n;
    float s1 = p.x, s2 = s1 + p.y, s3 = s2 + p.z;
    float4 sm = msk ? make_float4(0.f, s1, s2, s3) : ones;

    scan_prod(sm, buf, tid);
    float4 pfx = (tid > 0) ? buf[tid - 1] : ones;
    __syncthreads();

    buf[255 - tid] = sm;
    __syncthreads();
    float4 rsm = buf[tid];
    scan_prod(rsm, buf, tid);
    float4 sfx = (tid < 255) ? buf[254 - tid] : ones;

    float4 L = f4mul(pfx, sfx);
    float4 cpL = scan_prod(L, buf, tid);

    float4 term = msk ? f4mul(p, cpL) : make_float4(0.f, 0.f, 0.f, 0.f);
    float4 pm = msk ? p : ones;

    __syncthreads();
    buf[tid] = term;
    __syncthreads();
    for (int off = 128; off > 0; off >>= 1) {
        if (tid < off) {
            float4 a = buf[tid], c = buf[tid + off];
            buf[tid] = make_float4(a.x + c.x, a.y + c.y, a.z + c.z, a.w + c.w);
        }
        __syncthreads();
    }
    float4 sum_t = buf[0];
    __syncthreads();

    buf[tid] = pm;
    __syncthreads();
    for (int off = 128; off > 0; off >>= 1) {
        if (tid < off) buf[tid] = f4mul(buf[tid], buf[tid + off]);
        __syncthreads();
    }
    if (tid == 0) {
        float4 pr = buf[0];
        ((float4*)out)[b] = make_float4(0.25f * sum_t.x + pr.x,
                                        0.25f * sum_t.y + pr.y,
                                        0.25f * sum_t.z + pr.z,
                                        0.25f * sum_t.w + pr.w);
    }
}

extern "C" void kernel_launch(void* const* d_in, const int* in_sizes, int n_in,
                              void* d_out, int out_size, void* d_ws, size_t ws_size,
                              hipStream_t stream) {
    (void)in_sizes; (void)n_in; (void)out_size; (void)ws_size;
    const float* questions = (const float*)d_in[0];
    const float* segments  = (const float*)d_in[1];
    const float* W1 = (const float*)d_in[2];
    const float* b1 = (const float*)d_in[3];
    const float* W2 = (const float*)d_in[4];
    const float* b2 = (const float*)d_in[5];
    const float* W3 = (const float*)d_in[6];
    const float* b3 = (const float*)d_in[7];
    const int*  nseg = (const int*)d_in[8];
    float* out = (float*)d_out;

    char* w = (char*)d_ws;
    float* qW1p = (float*)w;           w += (size_t)4 * 128 * 768 * 4;
    unsigned short* W1t = (unsigned short*)w; w += (size_t)768 * 768 * 2;
    unsigned short* W2t = (unsigned short*)w; w += (size_t)384 * 768 * 2;
    unsigned short* segB = (unsigned short*)w; w += (size_t)32768 * 768 * 2;
    unsigned short* H1b  = (unsigned short*)w; w += (size_t)32768 * 768 * 2;
    unsigned short* H2b  = (unsigned short*)w; w += (size_t)32768 * 384 * 2;

    prep_kernel<<<PREP_END, 256, 0, stream>>>(
        segments, segB, W1, W1t, W2, W2t, questions, qW1p);
    // K2: 128x256 blocks (TJ=4)
    mfma_gemm_bt<4><<<dim3(3, 256), 256, 0, stream>>>(
        segB, W1t, b1, qW1p, H1b, 32768, 768, 768, 1);
    // K3: 128x128 blocks (TJ=2)
    mfma_gemm_bt<2><<<dim3(3, 256), 256, 0, stream>>>(
        H1b, W2t, b2, nullptr, H2b, 32768, 384, 768, 1);
    head_kernel<<<128, 256, 0, stream>>>(H2b, W3, b3, nseg, out);
}

// Round 9
// 323.342 us; speedup vs baseline: 1.0231x; 1.0231x over previous
//
#include <hip/hip_runtime.h>
#include <hip/hip_bf16.h>

// B=128, S=256, E=768, C=4; M = B*S = 32768.
// 4 launches:
//  prep:  qW1 partials (K-split x4) | W1t/W2t transposes | segB=bf16(segments)
//  K2:    H1b[32768,768]bf16 = gelu(segB @ W1t^T + b1 + sum qW1p[bag])
//  K3:    H2b[32768,384]bf16 = gelu(H1b @ W2t^T + b2)
//  head:  out[128,4] = aggregate(softmax(H2b @ W3 + b3))
// GEMM: 128x128 block, 4 waves, wave-tile 64x64 (2x2 of 32x32x16, 64 acc regs —
// r8 showed 128 acc regs collapses occupancy to 1 block/CU).
// A staged via global_load_lds + XOR swizzle; B-frags DIRECT global->VGPR
// (weights are L2-resident; halves LDS-pipe load). Grid (m,n) so the n-blocks
// of an m-strip share an XCD (id%8) -> A fetched once from HBM per strip.

typedef __attribute__((ext_vector_type(8))) short short8;
typedef __attribute__((ext_vector_type(8))) unsigned short ushort8;
typedef __attribute__((ext_vector_type(4))) float f32x4;
typedef __attribute__((ext_vector_type(16))) float f32x16;

__device__ __forceinline__ unsigned short f2bf(float f) {
    union { float f; unsigned int u; } c; c.f = f;
    unsigned int u = c.u;
    unsigned int r = (u + 0x7FFFu + ((u >> 16) & 1u)) >> 16;  // RNE
    return (unsigned short)r;
}
__device__ __forceinline__ float bf2f(unsigned short u) {
    union { unsigned int u; float f; } c; c.u = ((unsigned int)u) << 16;
    return c.f;
}
__device__ __forceinline__ float gelu_fast(float x) {
    float x2 = x * x;
    float y2 = 1.5957691216057308f * (x + 0.044715f * x2 * x);
    float e = __expf(y2);
    float t = 1.0f - 2.0f * __builtin_amdgcn_rcpf(e + 1.0f);
    return 0.5f * x * (1.0f + t);
}

typedef const __attribute__((address_space(1))) void* gas_t;
typedef __attribute__((address_space(3))) void* las_t;
__device__ __forceinline__ void g2l16(const void* g, void* l) {
    __builtin_amdgcn_global_load_lds((gas_t)g, (las_t)l, 16, 0, 0);
}

// ---------------- fused prep kernel ----------------
#define PREP_Q    96
#define PREP_TR1E 240
#define PREP_TR2E 312
#define PREP_END  12600

__global__ __launch_bounds__(256) void prep_kernel(
    const float* __restrict__ segments, unsigned short* __restrict__ segB,
    const float* __restrict__ W1, unsigned short* __restrict__ W1t,
    const float* __restrict__ W2, unsigned short* __restrict__ W2t,
    const float* __restrict__ questions, float* __restrict__ qW1p)
{
    __shared__ __align__(16) char sh[16640];
    const int bid = blockIdx.x, tid = threadIdx.x;

    if (bid < PREP_Q) {
        const int s = bid / 24, rem = bid % 24;
        const int n0 = (rem % 12) * 64, m0 = (rem / 12) * 64;
        float (*As)[64] = (float(*)[64])sh;
        float (*Bs)[64] = (float(*)[64])(sh + 4096);
        const int tn = tid & 15, tm = tid >> 4;
        float acc[4][4] = {};
        const int la_m = tid >> 2;
        const int la_k = (tid & 3) << 2;
        const int lb_k = tid >> 4;
        const int lb_n = (tid & 15) << 2;
        const float* Aptr = questions + (size_t)(m0 + la_m) * 768 + la_k;
        const float* Bptr = W1 + (size_t)lb_k * 768 + n0 + lb_n;
        const int kbeg = s * 192, kend = kbeg + 192;
        for (int k0 = kbeg; k0 < kend; k0 += 16) {
            float4 av = *(const float4*)(Aptr + k0);
            float4 bv = *(const float4*)(Bptr + (size_t)k0 * 768);
            As[la_k + 0][la_m] = av.x;
            As[la_k + 1][la_m] = av.y;
            As[la_k + 2][la_m] = av.z;
            As[la_k + 3][la_m] = av.w;
            *(float4*)&Bs[lb_k][lb_n] = bv;
            __syncthreads();
            #pragma unroll
            for (int k = 0; k < 16; k++) {
                float4 a = *(const float4*)&As[k][tm << 2];
                float4 b = *(const float4*)&Bs[k][tn << 2];
                float ar[4] = {a.x, a.y, a.z, a.w};
                float br[4] = {b.x, b.y, b.z, b.w};
                #pragma unroll
                for (int i = 0; i < 4; i++)
                    #pragma unroll
                    for (int j = 0; j < 4; j++)
                        acc[i][j] += ar[i] * br[j];
            }
            __syncthreads();
        }
        float* outp = qW1p + (size_t)s * 128 * 768;
        #pragma unroll
        for (int i = 0; i < 4; i++) {
            int row = m0 + (tm << 2) + i;
            int colBase = n0 + (tn << 2);
            *(float4*)&outp[(size_t)row * 768 + colBase] =
                make_float4(acc[i][0], acc[i][1], acc[i][2], acc[i][3]);
        }
        return;
    }

    if (bid < PREP_TR2E) {
        const float* in; unsigned short* outp; int R, C, bx, by;
        if (bid < PREP_TR1E) {
            int idx = bid - PREP_Q; bx = idx % 12; by = idx / 12;
            in = W1 + 768 * 768; outp = W1t; R = 768; C = 768;
        } else {
            int idx = bid - PREP_TR1E; bx = idx % 6; by = idx / 6;
            in = W2; outp = W2t; R = 768; C = 384;
        }
        float (*t)[65] = (float(*)[65])sh;
        int r0 = by * 64, c0 = bx * 64;
        int tx = tid & 63, ty = tid >> 6;
        #pragma unroll
        for (int p = 0; p < 16; p++) {
            int row = ty * 16 + p;
            t[row][tx] = in[(size_t)(r0 + row) * C + c0 + tx];
        }
        __syncthreads();
        #pragma unroll
        for (int p = 0; p < 16; p++) {
            int orow = ty * 16 + p;
            outp[(size_t)(c0 + orow) * R + r0 + tx] = f2bf(t[tx][orow]);
        }
        return;
    }

    {
        long i = (long)(bid - PREP_TR2E) * 256 + tid;
        const float4* in = (const float4*)segments;
        float4 a = in[2 * i], b = in[2 * i + 1];
        ushort8 o;
        o[0] = f2bf(a.x); o[1] = f2bf(a.y); o[2] = f2bf(a.z); o[3] = f2bf(a.w);
        o[4] = f2bf(b.x); o[5] = f2bf(b.y); o[6] = f2bf(b.z); o[7] = f2bf(b.w);
        *(ushort8*)(segB + i * 8) = o;
    }
}

// ---------------- bf16 MFMA GEMM: A via LDS (swizzled), B direct from global ----
// grid = (M/128, N/128): blockIdx.x = m-strip (so the N/128 blocks of a strip
// land on the same XCD via id%8), blockIdx.y = n.
__global__ __launch_bounds__(256) void mfma_gemm_bt(
    const unsigned short* __restrict__ A,    // [M,K] bf16
    const unsigned short* __restrict__ Bt,   // [N,K] bf16 (L2-resident weights)
    const float* __restrict__ bias,          // [N] or null
    const float* __restrict__ rowAdd,        // [4][M/256, N] partials or null
    unsigned short* __restrict__ Cout,       // [M,N] bf16
    int M, int N, int K, int applyGelu)
{
    __shared__ __align__(16) unsigned short smem[128 * 128];  // 32KB; K-loop uses 16KB As
    unsigned short* As = smem;             // [128][64] swizzled
    const int tid = threadIdx.x;
    const int wave = tid >> 6, lane = tid & 63;
    const int m0 = blockIdx.x * 128, n0 = blockIdx.y * 128;
    const int wm = (wave & 1) * 64;
    const int wcol = (wave >> 1) * 64;

    f32x16 acc[2][2] = {};

    // A staging: thread tid -> LDS row (tid>>3)+32r, chunk tid&7; src chunk XOR row.
    const int srow = tid >> 3;
    const int schunk = (tid & 7) ^ (srow & 7);
    const unsigned short* Ag = A + (size_t)(m0 + srow) * K + schunk * 8;
    unsigned short* Al = As + tid * 8;

    const int fm = lane & 31, fq = lane >> 5;
    const int fs = fm & 7;

    // B-frag base: lane reads row n0+wcol+j*32+fm, k-chunk fq*8 (+kh*16, +k0)
    const unsigned short* Bgf = Bt + (size_t)(n0 + wcol + fm) * K + fq * 8;

    for (int k0 = 0; k0 < K; k0 += 64) {
        // B-fragments direct global->VGPR (independent of the LDS barrier)
        short8 bfr[2][4];
        #pragma unroll
        for (int j = 0; j < 2; j++)
            #pragma unroll
            for (int kh = 0; kh < 4; kh++)
                bfr[j][kh] = *(const short8*)(Bgf + (size_t)j * 32 * K + k0 + kh * 16);

        #pragma unroll
        for (int r = 0; r < 4; r++)
            g2l16(Ag + k0 + (size_t)(32 * r) * K, Al + r * 2048);
        __syncthreads();

        #pragma unroll
        for (int kh = 0; kh < 4; kh++) {
            const int kc = (((kh << 1) | fq) ^ fs) * 8;
            short8 af[2];
            #pragma unroll
            for (int i = 0; i < 2; i++)
                af[i] = *(const short8*)&As[(wm + i * 32 + fm) * 64 + kc];
            #pragma unroll
            for (int i = 0; i < 2; i++)
                #pragma unroll
                for (int j = 0; j < 2; j++)
                    acc[i][j] = __builtin_amdgcn_mfma_f32_32x32x16_bf16(
                        af[i], bfr[j][kh], acc[i][j], 0, 0, 0);
        }
        __syncthreads();
    }

    // Epilogue: C/D layout col=lane&31, row=(reg&3)+8*(reg>>2)+4*(lane>>5)
    const float* radd = rowAdd ? (rowAdd + (size_t)(m0 >> 8) * N) : nullptr;
    #pragma unroll
    for (int j = 0; j < 2; j++) {
        int coll = wcol + j * 32 + fm;
        int col = n0 + coll;
        float add = bias ? bias[col] : 0.0f;
        if (radd)
            add += radd[col] + radd[col + 98304] +
                   radd[col + 2 * 98304] + radd[col + 3 * 98304];
        #pragma unroll
        for (int i = 0; i < 2; i++) {
            int rbase = wm + i * 32 + 4 * fq;
            #pragma unroll
            for (int reg = 0; reg < 16; reg++) {
                int rowl = rbase + (reg & 3) + 8 * (reg >> 2);
                float v = acc[i][j][reg] + add;
                if (applyGelu) v = gelu_fast(v);
                smem[rowl * 128 + coll] = f2bf(v);
            }
        }
    }
    __syncthreads();
    #pragma unroll
    for (int it = 0; it < 8; it++) {
        int idx = it * 256 + tid;
        int r = idx >> 4, cc = (idx & 15) * 8;
        *(ushort8*)&Cout[(size_t)(m0 + r) * N + n0 + cc] =
            *(const ushort8*)&smem[r * 128 + cc];
    }
}

// ---------------- fused head: layer3 + softmax + aggregation ----------------
__device__ __forceinline__ float4 f4mul(float4 a, float4 b) {
    return make_float4(a.x * b.x, a.y * b.y, a.z * b.z, a.w * b.w);
}
__device__ float4 scan_prod(float4 v, float4* buf, int tid) {
    __syncthreads();
    buf[tid] = v;
    __syncthreads();
    #pragma unroll
    for (int off = 1; off < 256; off <<= 1) {
        float4 o = (tid >= off) ? buf[tid - off] : make_float4(1.f, 1.f, 1.f, 1.f);
        __syncthreads();
        v = f4mul(v, o);
        buf[tid] = v;
        __syncthreads();
    }
    return v;
}

__global__ __launch_bounds__(256) void head_kernel(
    const unsigned short* __restrict__ H2, const float* __restrict__ W3,
    const float* __restrict__ b3, const int* __restrict__ nseg,
    float* __restrict__ out)
{
    __shared__ float4 buf[256];
    __shared__ float4 w3s[384];
    const int b = blockIdx.x, tid = threadIdx.x;
    for (int i = tid; i < 384; i += 256) w3s[i] = ((const float4*)W3)[i];
    __syncthreads();

    const unsigned short* hrow = H2 + (size_t)(b * 256 + tid) * 384;
    float4 acc = make_float4(b3[0], b3[1], b3[2], b3[3]);
    #pragma unroll
    for (int kk = 0; kk < 48; kk++) {
        ushort8 u = *(const ushort8*)(hrow + kk * 8);
        #pragma unroll
        for (int j = 0; j < 8; j++) {
            float h = bf2f(u[j]);
            float4 w = w3s[kk * 8 + j];
            acc.x += h * w.x; acc.y += h * w.y; acc.z += h * w.z; acc.w += h * w.w;
        }
    }
    float m = fmaxf(fmaxf(acc.x, acc.y), fmaxf(acc.z, acc.w));
    float e0 = __expf(acc.x - m), e1 = __expf(acc.y - m),
          e2 = __expf(acc.z - m), e3 = __expf(acc.w - m);
    float inv = 1.0f / (e0 + e1 + e2 + e3);
    float4 p = make_float4(e0 * inv, e1 * inv, e2 * inv, e3 * inv);

    const int n = nseg[b];
    const float4 ones = make_float4(1.f, 1.f, 1.f, 1.f);
    bool msk = tid < n;
    float s1 = p.x, s2 = s1 + p.y, s3 = s2 + p.z;
    float4 sm = msk ? make_float4(0.f, s1, s2, s3) : ones;

    scan_prod(sm, buf, tid);
    float4 pfx = (tid > 0) ? buf[tid - 1] : ones;
    __syncthreads();

    buf[255 - tid] = sm;
    __syncthreads();
    float4 rsm = buf[tid];
    scan_prod(rsm, buf, tid);
    float4 sfx = (tid < 255) ? buf[254 - tid] : ones;

    float4 L = f4mul(pfx, sfx);
    float4 cpL = scan_prod(L, buf, tid);

    float4 term = msk ? f4mul(p, cpL) : make_float4(0.f, 0.f, 0.f, 0.f);
    float4 pm = msk ? p : ones;

    __syncthreads();
    buf[tid] = term;
    __syncthreads();
    for (int off = 128; off > 0; off >>= 1) {
        if (tid < off) {
            float4 a = buf[tid], c = buf[tid + off];
            buf[tid] = make_float4(a.x + c.x, a.y + c.y, a.z + c.z, a.w + c.w);
        }
        __syncthreads();
    }
    float4 sum_t = buf[0];
    __syncthreads();

    buf[tid] = pm;
    __syncthreads();
    for (int off = 128; off > 0; off >>= 1) {
        if (tid < off) buf[tid] = f4mul(buf[tid], buf[tid + off]);
        __syncthreads();
    }
    if (tid == 0) {
        float4 pr = buf[0];
        ((float4*)out)[b] = make_float4(0.25f * sum_t.x + pr.x,
                                        0.25f * sum_t.y + pr.y,
                                        0.25f * sum_t.z + pr.z,
                                        0.25f * sum_t.w + pr.w);
    }
}

extern "C" void kernel_launch(void* const* d_in, const int* in_sizes, int n_in,
                              void* d_out, int out_size, void* d_ws, size_t ws_size,
                              hipStream_t stream) {
    (void)in_sizes; (void)n_in; (void)out_size; (void)ws_size;
    const float* questions = (const float*)d_in[0];
    const float* segments  = (const float*)d_in[1];
    const float* W1 = (const float*)d_in[2];
    const float* b1 = (const float*)d_in[3];
    const float* W2 = (const float*)d_in[4];
    const float* b2 = (const float*)d_in[5];
    const float* W3 = (const float*)d_in[6];
    const float* b3 = (const float*)d_in[7];
    const int*  nseg = (const int*)d_in[8];
    float* out = (float*)d_out;

    char* w = (char*)d_ws;
    float* qW1p = (float*)w;           w += (size_t)4 * 128 * 768 * 4;
    unsigned short* W1t = (unsigned short*)w; w += (size_t)768 * 768 * 2;
    unsigned short* W2t = (unsigned short*)w; w += (size_t)384 * 768 * 2;
    unsigned short* segB = (unsigned short*)w; w += (size_t)32768 * 768 * 2;
    unsigned short* H1b  = (unsigned short*)w; w += (size_t)32768 * 768 * 2;
    unsigned short* H2b  = (unsigned short*)w; w += (size_t)32768 * 384 * 2;

    prep_kernel<<<PREP_END, 256, 0, stream>>>(
        segments, segB, W1, W1t, W2, W2t, questions, qW1p);
    // K2: grid (m=256, n=6) — n-blocks of a strip share id%8 -> same XCD
    mfma_gemm_bt<<<dim3(256, 6), 256, 0, stream>>>(
        segB, W1t, b1, qW1p, H1b, 32768, 768, 768, 1);
    // K3: grid (m=256, n=3)
    mfma_gemm_bt<<<dim3(256, 3), 256, 0, stream>>>(
        H1b, W2t, b2, nullptr, H2b, 32768, 384, 768, 1);
    head_kernel<<<128, 256, 0, stream>>>(H2b, W3, b3, nseg, out);
}

// Round 10
// 254.557 us; speedup vs baseline: 1.2996x; 1.2702x over previous
//
#include <hip/hip_runtime.h>
#include <hip/hip_bf16.h>

// B=128, S=256, E=768, C=4; M = B*S = 32768.
// 4 launches:
//  prep:  qW1 partials (fp32) | W1t8=fp8(W1[768:].T) | W2t=bf16(W2.T) | segF8=fp8(segments)
//  K2:    H1b[32768,768]bf16 = gelu(segF8 @ W1t8^T + b1 + sum qW1p[bag])
//         -- MX-scaled fp8 MFMA 32x32x64 (unit scales), 128x128 block, 64x64 wave tile
//  K3:    H2b[32768,384]bf16 = gelu(H1b @ W2t^T + b2)   -- r6 bf16 32x32x16 kernel
//  head:  out[128,4] = aggregate(softmax(H2b @ W3 + b3))
// Error budget: only layer-1's segment half is fp8 (question half fp32 via qW1p);
// K3 bf16 -> predicted absmax ~1-2e-3 vs 6.9e-3 threshold.

typedef __attribute__((ext_vector_type(8))) short short8;
typedef __attribute__((ext_vector_type(8))) unsigned short ushort8;
typedef __attribute__((ext_vector_type(16))) float f32x16;
typedef __attribute__((ext_vector_type(8))) int i32x8;
typedef __attribute__((ext_vector_type(4))) int i32x4;

__device__ __forceinline__ unsigned short f2bf(float f) {
    union { float f; unsigned int u; } c; c.f = f;
    unsigned int u = c.u;
    unsigned int r = (u + 0x7FFFu + ((u >> 16) & 1u)) >> 16;  // RNE
    return (unsigned short)r;
}
__device__ __forceinline__ float bf2f(unsigned short u) {
    union { unsigned int u; float f; } c; c.u = ((unsigned int)u) << 16;
    return c.f;
}
__device__ __forceinline__ float gelu_fast(float x) {
    float x2 = x * x;
    float y2 = 1.5957691216057308f * (x + 0.044715f * x2 * x);
    float e = __expf(y2);
    float t = 1.0f - 2.0f * __builtin_amdgcn_rcpf(e + 1.0f);
    return 0.5f * x * (1.0f + t);
}

typedef const __attribute__((address_space(1))) void* gas_t;
typedef __attribute__((address_space(3))) void* las_t;
__device__ __forceinline__ void g2l16(const void* g, void* l) {
    __builtin_amdgcn_global_load_lds((gas_t)g, (las_t)l, 16, 0, 0);
}

// pack 4 floats -> 4 fp8 e4m3 bytes (RNE, saturating)
__device__ __forceinline__ unsigned int f4_to_fp8x4(float a, float b, float c, float d) {
    int lo = __builtin_amdgcn_cvt_pk_fp8_f32(a, b, 0, 0);      // bytes 0,1
    return (unsigned int)__builtin_amdgcn_cvt_pk_fp8_f32(c, d, lo, 1);  // bytes 2,3
}

// ---------------- fused prep kernel ----------------
// blocks [0,96):        qW1 partials fp32 (4 K-slices x 24 tiles)
// blocks [96,240):      transpose W1[768:] -> W1t8 (fp8)
// blocks [240,312):     transpose W2 -> W2t (bf16)
// blocks [312,12600):   conv segments -> segF8 (fp8)
#define PREP_Q    96
#define PREP_TR1E 240
#define PREP_TR2E 312
#define PREP_END  12600

__global__ __launch_bounds__(256) void prep_kernel(
    const float* __restrict__ segments, unsigned char* __restrict__ segF8,
    const float* __restrict__ W1, unsigned char* __restrict__ W1t8,
    const float* __restrict__ W2, unsigned short* __restrict__ W2t,
    const float* __restrict__ questions, float* __restrict__ qW1p)
{
    __shared__ __align__(16) char sh[16640];
    const int bid = blockIdx.x, tid = threadIdx.x;

    if (bid < PREP_Q) {
        const int s = bid / 24, rem = bid % 24;
        const int n0 = (rem % 12) * 64, m0 = (rem / 12) * 64;
        float (*As)[64] = (float(*)[64])sh;
        float (*Bs)[64] = (float(*)[64])(sh + 4096);
        const int tn = tid & 15, tm = tid >> 4;
        float acc[4][4] = {};
        const int la_m = tid >> 2;
        const int la_k = (tid & 3) << 2;
        const int lb_k = tid >> 4;
        const int lb_n = (tid & 15) << 2;
        const float* Aptr = questions + (size_t)(m0 + la_m) * 768 + la_k;
        const float* Bptr = W1 + (size_t)lb_k * 768 + n0 + lb_n;
        const int kbeg = s * 192, kend = kbeg + 192;
        for (int k0 = kbeg; k0 < kend; k0 += 16) {
            float4 av = *(const float4*)(Aptr + k0);
            float4 bv = *(const float4*)(Bptr + (size_t)k0 * 768);
            As[la_k + 0][la_m] = av.x;
            As[la_k + 1][la_m] = av.y;
            As[la_k + 2][la_m] = av.z;
            As[la_k + 3][la_m] = av.w;
            *(float4*)&Bs[lb_k][lb_n] = bv;
            __syncthreads();
            #pragma unroll
            for (int k = 0; k < 16; k++) {
                float4 a = *(const float4*)&As[k][tm << 2];
                float4 b = *(const float4*)&Bs[k][tn << 2];
                float ar[4] = {a.x, a.y, a.z, a.w};
                float br[4] = {b.x, b.y, b.z, b.w};
                #pragma unroll
                for (int i = 0; i < 4; i++)
                    #pragma unroll
                    for (int j = 0; j < 4; j++)
                        acc[i][j] += ar[i] * br[j];
            }
            __syncthreads();
        }
        float* outp = qW1p + (size_t)s * 128 * 768;
        #pragma unroll
        for (int i = 0; i < 4; i++) {
            int row = m0 + (tm << 2) + i;
            int colBase = n0 + (tn << 2);
            *(float4*)&outp[(size_t)row * 768 + colBase] =
                make_float4(acc[i][0], acc[i][1], acc[i][2], acc[i][3]);
        }
        return;
    }

    if (bid < PREP_TR2E) {
        // transpose 64x64 tile; W1seg -> fp8 bytes, W2 -> bf16
        const float* in; int R, C, bx, by, isF8;
        if (bid < PREP_TR1E) {
            int idx = bid - PREP_Q; bx = idx % 12; by = idx / 12;
            in = W1 + 768 * 768; R = 768; C = 768; isF8 = 1;
        } else {
            int idx = bid - PREP_TR1E; bx = idx % 6; by = idx / 6;
            in = W2; R = 768; C = 384; isF8 = 0;
        }
        float (*t)[65] = (float(*)[65])sh;
        int r0 = by * 64, c0 = bx * 64;
        int tx = tid & 63, ty = tid >> 6;
        #pragma unroll
        for (int p = 0; p < 16; p++) {
            int row = ty * 16 + p;
            t[row][tx] = in[(size_t)(r0 + row) * C + c0 + tx];
        }
        __syncthreads();
        #pragma unroll
        for (int p = 0; p < 16; p++) {
            int orow = ty * 16 + p;
            float v = t[tx][orow];
            if (isF8) {
                W1t8[(size_t)(c0 + orow) * R + r0 + tx] =
                    (unsigned char)(f4_to_fp8x4(v, 0.f, 0.f, 0.f) & 0xFF);
            } else {
                W2t[(size_t)(c0 + orow) * R + r0 + tx] = f2bf(v);
            }
        }
        return;
    }

    // conv: segments fp32 -> segF8 fp8 (8 elems/thread)
    {
        long i = (long)(bid - PREP_TR2E) * 256 + tid;
        const float4* in = (const float4*)segments;
        float4 a = in[2 * i], b = in[2 * i + 1];
        unsigned int lo = f4_to_fp8x4(a.x, a.y, a.z, a.w);
        unsigned int hi = f4_to_fp8x4(b.x, b.y, b.z, b.w);
        *(uint2*)(segF8 + i * 8) = make_uint2(lo, hi);
    }
}

// ---------------- fp8 MX-scaled MFMA GEMM (K2) ----------------
// C[M,N]bf16 = gelu(A8[M,K] @ Bt8[N,K]^T + bias + sum qW1p[bag])
// 128x128 block, 4 waves, wave 64x64 = 2x2 of 32x32x64 f8f6f4 (unit scales).
// LDS rows are 64 B (BK=64 fp8); swizzle key (row>>1)&3 so 8 consecutive rows
// sweep all 8 bank-groups (bank group = 4*(row&1) + chunk for 64-B rows).
__global__ __launch_bounds__(256) void mfma_gemm_f8(
    const unsigned char* __restrict__ A8,    // [M,K] fp8
    const unsigned char* __restrict__ Bt8,   // [N,K] fp8
    const float* __restrict__ bias,          // [N]
    const float* __restrict__ rowAdd,        // [4][128,N] partials
    unsigned short* __restrict__ Cout,       // [M,N] bf16
    int M, int N, int K)
{
    __shared__ __align__(16) unsigned char smem8[32768];
    unsigned char* As = smem8;             // [128][64B] swizzled (8KB)
    unsigned char* Bs = smem8 + 8192;      // [128][64B] (8KB)
    const int tid = threadIdx.x;
    const int wave = tid >> 6, lane = tid & 63;
    const int m0 = blockIdx.y * 128, n0 = blockIdx.x * 128;
    const int wm = (wave & 1) * 64, wn = (wave >> 1) * 64;

    f32x16 acc[2][2] = {};

    // staging: thread t -> LDS row t>>2 (+64/round), chunk t&3 (16B chunks)
    const int srow = tid >> 2;
    const int schunk = (tid & 3) ^ ((srow >> 1) & 3);
    const unsigned char* Ag = A8 + (size_t)(m0 + srow) * K + schunk * 16;
    const unsigned char* Bg = Bt8 + (size_t)(n0 + srow) * K + schunk * 16;
    unsigned char* Al = As + tid * 16;
    unsigned char* Bl = Bs + tid * 16;

    const int fm = lane & 31, fq = lane >> 5;

    for (int k0 = 0; k0 < K; k0 += 64) {
        g2l16(Ag + k0, Al);
        g2l16(Ag + (size_t)64 * K + k0, Al + 4096);
        g2l16(Bg + k0, Bl);
        g2l16(Bg + (size_t)64 * K + k0, Bl + 4096);
        __syncthreads();

        i32x8 av[2], bv[2];
        #pragma unroll
        for (int i = 0; i < 2; i++) {
            int rw = wm + i * 32 + fm, key = (rw >> 1) & 3;
            i32x4 lo = *(const i32x4*)&As[rw * 64 + (((fq << 1) | 0) ^ key) * 16];
            i32x4 hi = *(const i32x4*)&As[rw * 64 + (((fq << 1) | 1) ^ key) * 16];
            av[i][0] = lo[0]; av[i][1] = lo[1]; av[i][2] = lo[2]; av[i][3] = lo[3];
            av[i][4] = hi[0]; av[i][5] = hi[1]; av[i][6] = hi[2]; av[i][7] = hi[3];
        }
        #pragma unroll
        for (int j = 0; j < 2; j++) {
            int rw = wn + j * 32 + fm, key = (rw >> 1) & 3;
            i32x4 lo = *(const i32x4*)&Bs[rw * 64 + (((fq << 1) | 0) ^ key) * 16];
            i32x4 hi = *(const i32x4*)&Bs[rw * 64 + (((fq << 1) | 1) ^ key) * 16];
            bv[j][0] = lo[0]; bv[j][1] = lo[1]; bv[j][2] = lo[2]; bv[j][3] = lo[3];
            bv[j][4] = hi[0]; bv[j][5] = hi[1]; bv[j][6] = hi[2]; bv[j][7] = hi[3];
        }
        #pragma unroll
        for (int i = 0; i < 2; i++)
            #pragma unroll
            for (int j = 0; j < 2; j++)
                acc[i][j] = __builtin_amdgcn_mfma_scale_f32_32x32x64_f8f6f4(
                    av[i], bv[j], acc[i][j], 0, 0,   // cbsz=fp8, blgp=fp8
                    0, 127, 0, 127);                 // unit e8m0 scales
        __syncthreads();
    }

    // Epilogue (C/D: col=lane&31, row=(reg&3)+8*(reg>>2)+4*(lane>>5)), gelu + bf16
    unsigned short* cst = (unsigned short*)smem8;
    const float* radd = rowAdd + (size_t)(m0 >> 8) * N;
    #pragma unroll
    for (int j = 0; j < 2; j++) {
        int coll = wn + j * 32 + fm;
        int col = n0 + coll;
        float add = bias[col] + radd[col] + radd[col + 98304] +
                    radd[col + 2 * 98304] + radd[col + 3 * 98304];
        #pragma unroll
        for (int i = 0; i < 2; i++) {
            int rbase = wm + i * 32 + 4 * fq;
            #pragma unroll
            for (int reg = 0; reg < 16; reg++) {
                int rowl = rbase + (reg & 3) + 8 * (reg >> 2);
                cst[rowl * 128 + coll] = f2bf(gelu_fast(acc[i][j][reg] + add));
            }
        }
    }
    __syncthreads();
    #pragma unroll
    for (int it = 0; it < 8; it++) {
        int idx = it * 256 + tid;
        int r = idx >> 4, cc = (idx & 15) * 8;
        *(ushort8*)&Cout[(size_t)(m0 + r) * N + n0 + cc] =
            *(const ushort8*)&cst[r * 128 + cc];
    }
}

// ---------------- bf16 MFMA GEMM (K3, r6-proven) ----------------
__global__ __launch_bounds__(256) void mfma_gemm_bt(
    const unsigned short* __restrict__ A,
    const unsigned short* __restrict__ Bt,
    const float* __restrict__ bias,
    unsigned short* __restrict__ Cout,
    int M, int N, int K, int applyGelu)
{
    __shared__ __align__(16) unsigned short smem[128 * 128];
    unsigned short* As = smem;
    unsigned short* Bs = smem + 8192;
    const int tid = threadIdx.x;
    const int wave = tid >> 6, lane = tid & 63;
    const int m0 = blockIdx.y * 128, n0 = blockIdx.x * 128;
    const int wm = (wave & 1) * 64, wn = (wave >> 1) * 64;

    f32x16 acc[2][2] = {};

    const int srow = tid >> 3;
    const int schunk = (tid & 7) ^ (srow & 7);
    const unsigned short* Ag = A + (size_t)(m0 + srow) * K + schunk * 8;
    const unsigned short* Bg = Bt + (size_t)(n0 + srow) * K + schunk * 8;
    unsigned short* Al = As + tid * 8;
    unsigned short* Bl = Bs + tid * 8;

    const int fm = lane & 31, fq = lane >> 5;
    const int fs = fm & 7;

    for (int k0 = 0; k0 < K; k0 += 64) {
        #pragma unroll
        for (int r = 0; r < 4; r++) {
            g2l16(Ag + k0 + (size_t)(32 * r) * K, Al + r * 2048);
            g2l16(Bg + k0 + (size_t)(32 * r) * K, Bl + r * 2048);
        }
        __syncthreads();

        short8 af[2][4], bfr[2][4];
        #pragma unroll
        for (int i = 0; i < 2; i++)
            #pragma unroll
            for (int kh = 0; kh < 4; kh++)
                af[i][kh] = *(const short8*)
                    &As[(wm + i * 32 + fm) * 64 + (((kh << 1) | fq) ^ fs) * 8];
        #pragma unroll
        for (int j = 0; j < 2; j++)
            #pragma unroll
            for (int kh = 0; kh < 4; kh++)
                bfr[j][kh] = *(const short8*)
                    &Bs[(wn + j * 32 + fm) * 64 + (((kh << 1) | fq) ^ fs) * 8];
        #pragma unroll
        for (int kh = 0; kh < 4; kh++)
            #pragma unroll
            for (int i = 0; i < 2; i++)
                #pragma unroll
                for (int j = 0; j < 2; j++)
                    acc[i][j] = __builtin_amdgcn_mfma_f32_32x32x16_bf16(
                        af[i][kh], bfr[j][kh], acc[i][j], 0, 0, 0);
        __syncthreads();
    }

    #pragma unroll
    for (int j = 0; j < 2; j++) {
        int coll = wn + j * 32 + fm;
        int col = n0 + coll;
        float add = bias ? bias[col] : 0.0f;
        #pragma unroll
        for (int i = 0; i < 2; i++) {
            int rbase = wm + i * 32 + 4 * fq;
            #pragma unroll
            for (int reg = 0; reg < 16; reg++) {
                int rowl = rbase + (reg & 3) + 8 * (reg >> 2);
                float v = acc[i][j][reg] + add;
                if (applyGelu) v = gelu_fast(v);
                smem[rowl * 128 + coll] = f2bf(v);
            }
        }
    }
    __syncthreads();
    #pragma unroll
    for (int it = 0; it < 8; it++) {
        int idx = it * 256 + tid;
        int r = idx >> 4, cc = (idx & 15) * 8;
        *(ushort8*)&Cout[(size_t)(m0 + r) * N + n0 + cc] =
            *(const ushort8*)&smem[r * 128 + cc];
    }
}

// ---------------- fused head: layer3 + softmax + aggregation ----------------
__device__ __forceinline__ float4 f4mul(float4 a, float4 b) {
    return make_float4(a.x * b.x, a.y * b.y, a.z * b.z, a.w * b.w);
}
__device__ float4 scan_prod(float4 v, float4* buf, int tid) {
    __syncthreads();
    buf[tid] = v;
    __syncthreads();
    #pragma unroll
    for (int off = 1; off < 256; off <<= 1) {
        float4 o = (tid >= off) ? buf[tid - off] : make_float4(1.f, 1.f, 1.f, 1.f);
        __syncthreads();
        v = f4mul(v, o);
        buf[tid] = v;
        __syncthreads();
    }
    return v;
}

__global__ __launch_bounds__(256) void head_kernel(
    const unsigned short* __restrict__ H2, const float* __restrict__ W3,
    const float* __restrict__ b3, const int* __restrict__ nseg,
    float* __restrict__ out)
{
    __shared__ float4 buf[256];
    __shared__ float4 w3s[384];
    const int b = blockIdx.x, tid = threadIdx.x;
    for (int i = tid; i < 384; i += 256) w3s[i] = ((const float4*)W3)[i];
    __syncthreads();

    const unsigned short* hrow = H2 + (size_t)(b * 256 + tid) * 384;
    float4 acc = make_float4(b3[0], b3[1], b3[2], b3[3]);
    #pragma unroll
    for (int kk = 0; kk < 48; kk++) {
        ushort8 u = *(const ushort8*)(hrow + kk * 8);
        #pragma unroll
        for (int j = 0; j < 8; j++) {
            float h = bf2f(u[j]);
            float4 w = w3s[kk * 8 + j];
            acc.x += h * w.x; acc.y += h * w.y; acc.z += h * w.z; acc.w += h * w.w;
        }
    }
    float m = fmaxf(fmaxf(acc.x, acc.y), fmaxf(acc.z, acc.w));
    float e0 = __expf(acc.x - m), e1 = __expf(acc.y - m),
          e2 = __expf(acc.z - m), e3 = __expf(acc.w - m);
    float inv = 1.0f / (e0 + e1 + e2 + e3);
    float4 p = make_float4(e0 * inv, e1 * inv, e2 * inv, e3 * inv);

    const int n = nseg[b];
    const float4 ones = make_float4(1.f, 1.f, 1.f, 1.f);
    bool msk = tid < n;
    float s1 = p.x, s2 = s1 + p.y, s3 = s2 + p.z;
    float4 sm = msk ? make_float4(0.f, s1, s2, s3) : ones;

    scan_prod(sm, buf, tid);
    float4 pfx = (tid > 0) ? buf[tid - 1] : ones;
    __syncthreads();

    buf[255 - tid] = sm;
    __syncthreads();
    float4 rsm = buf[tid];
    scan_prod(rsm, buf, tid);
    float4 sfx = (tid < 255) ? buf[254 - tid] : ones;

    float4 L = f4mul(pfx, sfx);
    float4 cpL = scan_prod(L, buf, tid);

    float4 term = msk ? f4mul(p, cpL) : make_float4(0.f, 0.f, 0.f, 0.f);
    float4 pm = msk ? p : ones;

    __syncthreads();
    buf[tid] = term;
    __syncthreads();
    for (int off = 128; off > 0; off >>= 1) {
        if (tid < off) {
            float4 a = buf[tid], c = buf[tid + off];
            buf[tid] = make_float4(a.x + c.x, a.y + c.y, a.z + c.z, a.w + c.w);
        }
        __syncthreads();
    }
    float4 sum_t = buf[0];
    __syncthreads();

    buf[tid] = pm;
    __syncthreads();
    for (int off = 128; off > 0; off >>= 1) {
        if (tid < off) buf[tid] = f4mul(buf[tid], buf[tid + off]);
        __syncthreads();
    }
    if (tid == 0) {
        float4 pr = buf[0];
        ((float4*)out)[b] = make_float4(0.25f * sum_t.x + pr.x,
                                        0.25f * sum_t.y + pr.y,
                                        0.25f * sum_t.z + pr.z,
                                        0.25f * sum_t.w + pr.w);
    }
}

extern "C" void kernel_launch(void* const* d_in, const int* in_sizes, int n_in,
                              void* d_out, int out_size, void* d_ws, size_t ws_size,
                              hipStream_t stream) {
    (void)in_sizes; (void)n_in; (void)out_size; (void)ws_size;
    const float* questions = (const float*)d_in[0];
    const float* segments  = (const float*)d_in[1];
    const float* W1 = (const float*)d_in[2];
    const float* b1 = (const float*)d_in[3];
    const float* W2 = (const float*)d_in[4];
    const float* b2 = (const float*)d_in[5];
    const float* W3 = (const float*)d_in[6];
    const float* b3 = (const float*)d_in[7];
    const int*  nseg = (const int*)d_in[8];
    float* out = (float*)d_out;

    char* w = (char*)d_ws;
    float* qW1p = (float*)w;                   w += (size_t)4 * 128 * 768 * 4;
    unsigned char*  W1t8 = (unsigned char*)w;  w += (size_t)768 * 768;
    unsigned short* W2t = (unsigned short*)w;  w += (size_t)384 * 768 * 2;
    unsigned char*  segF8 = (unsigned char*)w; w += (size_t)32768 * 768;
    unsigned short* H1b  = (unsigned short*)w; w += (size_t)32768 * 768 * 2;
    unsigned short* H2b  = (unsigned short*)w; w += (size_t)32768 * 384 * 2;

    prep_kernel<<<PREP_END, 256, 0, stream>>>(
        segments, segF8, W1, W1t8, W2, W2t, questions, qW1p);
    // K2 (fp8 MX): grid (n=6, m=256)
    mfma_gemm_f8<<<dim3(6, 256), 256, 0, stream>>>(
        segF8, W1t8, b1, qW1p, H1b, 32768, 768, 768);
    // K3 (bf16): grid (n=3, m=256)
    mfma_gemm_bt<<<dim3(3, 256), 256, 0, stream>>>(
        H1b, W2t, b2, H2b, 32768, 384, 768, 1);
    head_kernel<<<128, 256, 0, stream>>>(H2b, W3, b3, nseg, out);
}

// Round 11
// 245.231 us; speedup vs baseline: 1.3490x; 1.0380x over previous
//
#include <hip/hip_runtime.h>
#include <hip/hip_bf16.h>

// B=128, S=256, E=768, C=4; M = B*S = 32768.
// 4 launches:
//  prep:  qW1 partials (fp32) | W1t8=fp8(W1[768:].T) | W2t8=fp8(W2.T) | segF8=fp8(segments)
//  K2:    H1f8[32768,768]fp8 = gelu(segF8 @ W1t8^T + b1 + sum qW1p[bag])   (fp8-MX MFMA)
//  K3:    H2b[32768,384]bf16 = gelu(H1f8 @ W2t8^T + b2)                    (fp8-MX MFMA)
//  head:  out[128,4] = aggregate(softmax(H2b @ W3 + b3))
// Error budget: r10 (K2-only fp8) measured 1.95e-3; K3-fp8 adds a comparable
// one-layer-later contribution -> predicted ~3-4e-3 vs 6.9e-3 threshold.

typedef __attribute__((ext_vector_type(8))) short short8;
typedef __attribute__((ext_vector_type(8))) unsigned short ushort8;
typedef __attribute__((ext_vector_type(16))) float f32x16;
typedef __attribute__((ext_vector_type(8))) int i32x8;
typedef __attribute__((ext_vector_type(4))) int i32x4;

__device__ __forceinline__ unsigned short f2bf(float f) {
    union { float f; unsigned int u; } c; c.f = f;
    unsigned int u = c.u;
    unsigned int r = (u + 0x7FFFu + ((u >> 16) & 1u)) >> 16;  // RNE
    return (unsigned short)r;
}
__device__ __forceinline__ float bf2f(unsigned short u) {
    union { unsigned int u; float f; } c; c.u = ((unsigned int)u) << 16;
    return c.f;
}
__device__ __forceinline__ float gelu_fast(float x) {
    float x2 = x * x;
    float y2 = 1.5957691216057308f * (x + 0.044715f * x2 * x);
    float e = __expf(y2);
    float t = 1.0f - 2.0f * __builtin_amdgcn_rcpf(e + 1.0f);
    return 0.5f * x * (1.0f + t);
}

typedef const __attribute__((address_space(1))) void* gas_t;
typedef __attribute__((address_space(3))) void* las_t;
__device__ __forceinline__ void g2l16(const void* g, void* l) {
    __builtin_amdgcn_global_load_lds((gas_t)g, (las_t)l, 16, 0, 0);
}

// pack 4 floats -> 4 fp8 e4m3 bytes (RNE, saturating)
__device__ __forceinline__ unsigned int f4_to_fp8x4(float a, float b, float c, float d) {
    int lo = __builtin_amdgcn_cvt_pk_fp8_f32(a, b, 0, 0);
    return (unsigned int)__builtin_amdgcn_cvt_pk_fp8_f32(c, d, lo, 1);
}
__device__ __forceinline__ unsigned char f_to_fp8(float a) {
    return (unsigned char)(__builtin_amdgcn_cvt_pk_fp8_f32(a, a, 0, 0) & 0xFF);
}

// ---------------- fused prep kernel ----------------
#define PREP_Q    96
#define PREP_TR1E 240
#define PREP_TR2E 312
#define PREP_END  12600

__global__ __launch_bounds__(256) void prep_kernel(
    const float* __restrict__ segments, unsigned char* __restrict__ segF8,
    const float* __restrict__ W1, unsigned char* __restrict__ W1t8,
    const float* __restrict__ W2, unsigned char* __restrict__ W2t8,
    const float* __restrict__ questions, float* __restrict__ qW1p)
{
    __shared__ __align__(16) char sh[16640];
    const int bid = blockIdx.x, tid = threadIdx.x;

    if (bid < PREP_Q) {
        const int s = bid / 24, rem = bid % 24;
        const int n0 = (rem % 12) * 64, m0 = (rem / 12) * 64;
        float (*As)[64] = (float(*)[64])sh;
        float (*Bs)[64] = (float(*)[64])(sh + 4096);
        const int tn = tid & 15, tm = tid >> 4;
        float acc[4][4] = {};
        const int la_m = tid >> 2;
        const int la_k = (tid & 3) << 2;
        const int lb_k = tid >> 4;
        const int lb_n = (tid & 15) << 2;
        const float* Aptr = questions + (size_t)(m0 + la_m) * 768 + la_k;
        const float* Bptr = W1 + (size_t)lb_k * 768 + n0 + lb_n;
        const int kbeg = s * 192, kend = kbeg + 192;
        for (int k0 = kbeg; k0 < kend; k0 += 16) {
            float4 av = *(const float4*)(Aptr + k0);
            float4 bv = *(const float4*)(Bptr + (size_t)k0 * 768);
            As[la_k + 0][la_m] = av.x;
            As[la_k + 1][la_m] = av.y;
            As[la_k + 2][la_m] = av.z;
            As[la_k + 3][la_m] = av.w;
            *(float4*)&Bs[lb_k][lb_n] = bv;
            __syncthreads();
            #pragma unroll
            for (int k = 0; k < 16; k++) {
                float4 a = *(const float4*)&As[k][tm << 2];
                float4 b = *(const float4*)&Bs[k][tn << 2];
                float ar[4] = {a.x, a.y, a.z, a.w};
                float br[4] = {b.x, b.y, b.z, b.w};
                #pragma unroll
                for (int i = 0; i < 4; i++)
                    #pragma unroll
                    for (int j = 0; j < 4; j++)
                        acc[i][j] += ar[i] * br[j];
            }
            __syncthreads();
        }
        float* outp = qW1p + (size_t)s * 128 * 768;
        #pragma unroll
        for (int i = 0; i < 4; i++) {
            int row = m0 + (tm << 2) + i;
            int colBase = n0 + (tn << 2);
            *(float4*)&outp[(size_t)row * 768 + colBase] =
                make_float4(acc[i][0], acc[i][1], acc[i][2], acc[i][3]);
        }
        return;
    }

    if (bid < PREP_TR2E) {
        // transpose 64x64 tile -> fp8 bytes
        const float* in; unsigned char* outp; int R, C, bx, by;
        if (bid < PREP_TR1E) {
            int idx = bid - PREP_Q; bx = idx % 12; by = idx / 12;
            in = W1 + 768 * 768; outp = W1t8; R = 768; C = 768;
        } else {
            int idx = bid - PREP_TR1E; bx = idx % 6; by = idx / 6;
            in = W2; outp = W2t8; R = 768; C = 384;
        }
        float (*t)[65] = (float(*)[65])sh;
        int r0 = by * 64, c0 = bx * 64;
        int tx = tid & 63, ty = tid >> 6;
        #pragma unroll
        for (int p = 0; p < 16; p++) {
            int row = ty * 16 + p;
            t[row][tx] = in[(size_t)(r0 + row) * C + c0 + tx];
        }
        __syncthreads();
        #pragma unroll
        for (int p = 0; p < 16; p++) {
            int orow = ty * 16 + p;
            outp[(size_t)(c0 + orow) * R + r0 + tx] = f_to_fp8(t[tx][orow]);
        }
        return;
    }

    // conv: segments fp32 -> segF8 fp8 (8 elems/thread)
    {
        long i = (long)(bid - PREP_TR2E) * 256 + tid;
        const float4* in = (const float4*)segments;
        float4 a = in[2 * i], b = in[2 * i + 1];
        unsigned int lo = f4_to_fp8x4(a.x, a.y, a.z, a.w);
        unsigned int hi = f4_to_fp8x4(b.x, b.y, b.z, b.w);
        *(uint2*)(segF8 + i * 8) = make_uint2(lo, hi);
    }
}

// ---------------- fp8 MX-scaled MFMA GEMM ----------------
// C[M,N] = gelu(A8[M,K] @ Bt8[N,K]^T + bias + optional sum qW1p[bag])
// OUT8=1: output fp8 bytes; OUT8=0: output bf16.
// 128x128 block, 4 waves, wave 64x64 = 2x2 of 32x32x64 f8f6f4 (unit scales).
template<int OUT8>
__global__ __launch_bounds__(256) void mfma_gemm_f8(
    const unsigned char* __restrict__ A8,    // [M,K] fp8
    const unsigned char* __restrict__ Bt8,   // [N,K] fp8
    const float* __restrict__ bias,          // [N]
    const float* __restrict__ rowAdd,        // [4][128,N] partials or null
    void* __restrict__ CoutV,                // [M,N] fp8 or bf16
    int M, int N, int K)
{
    __shared__ __align__(16) unsigned char smem8[32768];
    unsigned char* As = smem8;             // [128][64B] swizzled (8KB)
    unsigned char* Bs = smem8 + 8192;      // [128][64B] (8KB)
    const int tid = threadIdx.x;
    const int wave = tid >> 6, lane = tid & 63;
    const int m0 = blockIdx.y * 128, n0 = blockIdx.x * 128;
    const int wm = (wave & 1) * 64, wn = (wave >> 1) * 64;

    f32x16 acc[2][2] = {};

    const int srow = tid >> 2;
    const int schunk = (tid & 3) ^ ((srow >> 1) & 3);
    const unsigned char* Ag = A8 + (size_t)(m0 + srow) * K + schunk * 16;
    const unsigned char* Bg = Bt8 + (size_t)(n0 + srow) * K + schunk * 16;
    unsigned char* Al = As + tid * 16;
    unsigned char* Bl = Bs + tid * 16;

    const int fm = lane & 31, fq = lane >> 5;

    for (int k0 = 0; k0 < K; k0 += 64) {
        g2l16(Ag + k0, Al);
        g2l16(Ag + (size_t)64 * K + k0, Al + 4096);
        g2l16(Bg + k0, Bl);
        g2l16(Bg + (size_t)64 * K + k0, Bl + 4096);
        __syncthreads();

        i32x8 av[2], bv[2];
        #pragma unroll
        for (int i = 0; i < 2; i++) {
            int rw = wm + i * 32 + fm, key = (rw >> 1) & 3;
            i32x4 lo = *(const i32x4*)&As[rw * 64 + (((fq << 1) | 0) ^ key) * 16];
            i32x4 hi = *(const i32x4*)&As[rw * 64 + (((fq << 1) | 1) ^ key) * 16];
            av[i][0] = lo[0]; av[i][1] = lo[1]; av[i][2] = lo[2]; av[i][3] = lo[3];
            av[i][4] = hi[0]; av[i][5] = hi[1]; av[i][6] = hi[2]; av[i][7] = hi[3];
        }
        #pragma unroll
        for (int j = 0; j < 2; j++) {
            int rw = wn + j * 32 + fm, key = (rw >> 1) & 3;
            i32x4 lo = *(const i32x4*)&Bs[rw * 64 + (((fq << 1) | 0) ^ key) * 16];
            i32x4 hi = *(const i32x4*)&Bs[rw * 64 + (((fq << 1) | 1) ^ key) * 16];
            bv[j][0] = lo[0]; bv[j][1] = lo[1]; bv[j][2] = lo[2]; bv[j][3] = lo[3];
            bv[j][4] = hi[0]; bv[j][5] = hi[1]; bv[j][6] = hi[2]; bv[j][7] = hi[3];
        }
        #pragma unroll
        for (int i = 0; i < 2; i++)
            #pragma unroll
            for (int j = 0; j < 2; j++)
                acc[i][j] = __builtin_amdgcn_mfma_scale_f32_32x32x64_f8f6f4(
                    av[i], bv[j], acc[i][j], 0, 0,   // cbsz=fp8, blgp=fp8
                    0, 127, 0, 127);                 // unit e8m0 scales
        __syncthreads();
    }

    // Epilogue (C/D: col=lane&31, row=(reg&3)+8*(reg>>2)+4*(lane>>5)), gelu
    #pragma unroll
    for (int j = 0; j < 2; j++) {
        int coll = wn + j * 32 + fm;
        int col = n0 + coll;
        float add = bias[col];
        if (rowAdd) {
            const float* radd = rowAdd + (size_t)(m0 >> 8) * N;
            add += radd[col] + radd[col + 98304] +
                   radd[col + 2 * 98304] + radd[col + 3 * 98304];
        }
        #pragma unroll
        for (int i = 0; i < 2; i++) {
            int rbase = wm + i * 32 + 4 * fq;
            #pragma unroll
            for (int reg = 0; reg < 16; reg++) {
                int rowl = rbase + (reg & 3) + 8 * (reg >> 2);
                float v = gelu_fast(acc[i][j][reg] + add);
                if (OUT8) smem8[rowl * 128 + coll] = f_to_fp8(v);
                else ((unsigned short*)smem8)[rowl * 128 + coll] = f2bf(v);
            }
        }
    }
    __syncthreads();
    if (OUT8) {
        unsigned char* Cout = (unsigned char*)CoutV;
        #pragma unroll
        for (int it = 0; it < 4; it++) {
            int idx = it * 256 + tid;
            int r = idx >> 3, cc = (idx & 7) * 16;
            *(uint4*)&Cout[(size_t)(m0 + r) * N + n0 + cc] =
                *(const uint4*)&smem8[r * 128 + cc];
        }
    } else {
        unsigned short* Cout = (unsigned short*)CoutV;
        #pragma unroll
        for (int it = 0; it < 8; it++) {
            int idx = it * 256 + tid;
            int r = idx >> 4, cc = (idx & 15) * 8;
            *(ushort8*)&Cout[(size_t)(m0 + r) * N + n0 + cc] =
                *(const ushort8*)&((unsigned short*)smem8)[r * 128 + cc];
        }
    }
}

// ---------------- fused head: layer3 + softmax + aggregation ----------------
__device__ __forceinline__ float4 f4mul(float4 a, float4 b) {
    return make_float4(a.x * b.x, a.y * b.y, a.z * b.z, a.w * b.w);
}
__device__ float4 scan_prod(float4 v, float4* buf, int tid) {
    __syncthreads();
    buf[tid] = v;
    __syncthreads();
    #pragma unroll
    for (int off = 1; off < 256; off <<= 1) {
        float4 o = (tid >= off) ? buf[tid - off] : make_float4(1.f, 1.f, 1.f, 1.f);
        __syncthreads();
        v = f4mul(v, o);
        buf[tid] = v;
        __syncthreads();
    }
    return v;
}

__global__ __launch_bounds__(256) void head_kernel(
    const unsigned short* __restrict__ H2, const float* __restrict__ W3,
    const float* __restrict__ b3, const int* __restrict__ nseg,
    float* __restrict__ out)
{
    __shared__ float4 buf[256];
    __shared__ float4 w3s[384];
    const int b = blockIdx.x, tid = threadIdx.x;
    for (int i = tid; i < 384; i += 256) w3s[i] = ((const float4*)W3)[i];
    __syncthreads();

    const unsigned short* hrow = H2 + (size_t)(b * 256 + tid) * 384;
    float4 acc = make_float4(b3[0], b3[1], b3[2], b3[3]);
    #pragma unroll
    for (int kk = 0; kk < 48; kk++) {
        ushort8 u = *(const ushort8*)(hrow + kk * 8);
        #pragma unroll
        for (int j = 0; j < 8; j++) {
            float h = bf2f(u[j]);
            float4 w = w3s[kk * 8 + j];
            acc.x += h * w.x; acc.y += h * w.y; acc.z += h * w.z; acc.w += h * w.w;
        }
    }
    float m = fmaxf(fmaxf(acc.x, acc.y), fmaxf(acc.z, acc.w));
    float e0 = __expf(acc.x - m), e1 = __expf(acc.y - m),
          e2 = __expf(acc.z - m), e3 = __expf(acc.w - m);
    float inv = 1.0f / (e0 + e1 + e2 + e3);
    float4 p = make_float4(e0 * inv, e1 * inv, e2 * inv, e3 * inv);

    const int n = nseg[b];
    const float4 ones = make_float4(1.f, 1.f, 1.f, 1.f);
    bool msk = tid < n;
    float s1 = p.x, s2 = s1 + p.y, s3 = s2 + p.z;
    float4 sm = msk ? make_float4(0.f, s1, s2, s3) : ones;

    scan_prod(sm, buf, tid);
    float4 pfx = (tid > 0) ? buf[tid - 1] : ones;
    __syncthreads();

    buf[255 - tid] = sm;
    __syncthreads();
    float4 rsm = buf[tid];
    scan_prod(rsm, buf, tid);
    float4 sfx = (tid < 255) ? buf[254 - tid] : ones;

    float4 L = f4mul(pfx, sfx);
    float4 cpL = scan_prod(L, buf, tid);

    float4 term = msk ? f4mul(p, cpL) : make_float4(0.f, 0.f, 0.f, 0.f);
    float4 pm = msk ? p : ones;

    __syncthreads();
    buf[tid] = term;
    __syncthreads();
    for (int off = 128; off > 0; off >>= 1) {
        if (tid < off) {
            float4 a = buf[tid], c = buf[tid + off];
            buf[tid] = make_float4(a.x + c.x, a.y + c.y, a.z + c.z, a.w + c.w);
        }
        __syncthreads();
    }
    float4 sum_t = buf[0];
    __syncthreads();

    buf[tid] = pm;
    __syncthreads();
    for (int off = 128; off > 0; off >>= 1) {
        if (tid < off) buf[tid] = f4mul(buf[tid], buf[tid + off]);
        __syncthreads();
    }
    if (tid == 0) {
        float4 pr = buf[0];
        ((float4*)out)[b] = make_float4(0.25f * sum_t.x + pr.x,
                                        0.25f * sum_t.y + pr.y,
                                        0.25f * sum_t.z + pr.z,
                                        0.25f * sum_t.w + pr.w);
    }
}

extern "C" void kernel_launch(void* const* d_in, const int* in_sizes, int n_in,
                              void* d_out, int out_size, void* d_ws, size_t ws_size,
                              hipStream_t stream) {
    (void)in_sizes; (void)n_in; (void)out_size; (void)ws_size;
    const float* questions = (const float*)d_in[0];
    const float* segments  = (const float*)d_in[1];
    const float* W1 = (const float*)d_in[2];
    const float* b1 = (const float*)d_in[3];
    const float* W2 = (const float*)d_in[4];
    const float* b2 = (const float*)d_in[5];
    const float* W3 = (const float*)d_in[6];
    const float* b3 = (const float*)d_in[7];
    const int*  nseg = (const int*)d_in[8];
    float* out = (float*)d_out;

    char* w = (char*)d_ws;
    float* qW1p = (float*)w;                   w += (size_t)4 * 128 * 768 * 4;
    unsigned char*  W1t8 = (unsigned char*)w;  w += (size_t)768 * 768;
    unsigned char*  W2t8 = (unsigned char*)w;  w += (size_t)384 * 768;
    unsigned char*  segF8 = (unsigned char*)w; w += (size_t)32768 * 768;
    unsigned char*  H1f8 = (unsigned char*)w;  w += (size_t)32768 * 768;
    unsigned short* H2b  = (unsigned short*)w; w += (size_t)32768 * 384 * 2;

    prep_kernel<<<PREP_END, 256, 0, stream>>>(
        segments, segF8, W1, W1t8, W2, W2t8, questions, qW1p);
    // K2 (fp8 -> fp8): grid (n=6, m=256)
    mfma_gemm_f8<1><<<dim3(6, 256), 256, 0, stream>>>(
        segF8, W1t8, b1, qW1p, H1f8, 32768, 768, 768);
    // K3 (fp8 -> bf16): grid (n=3, m=256)
    mfma_gemm_f8<0><<<dim3(3, 256), 256, 0, stream>>>(
        H1f8, W2t8, b2, nullptr, H2b, 32768, 384, 768);
    head_kernel<<<128, 256, 0, stream>>>(H2b, W3, b3, nseg, out);
}